// Round 1
// baseline (1356.581 us; speedup 1.0000x reference)
//
#include <hip/hip_runtime.h>
#include <stdint.h>

// Problem constants
#define B_    32
#define L_    512
#define DIN_  768
#define H_    16
#define DH_   48
#define DOUT_ 768
#define NHEADS (B_ * H_)          // 512
#define HEADELEMS (L_ * DH_)      // 24576 elems per head

// ---------------------------------------------------------------------------
// bf16 helpers (manual, RNE)
// ---------------------------------------------------------------------------
__device__ inline uint16_t f2bf(float f) {
  uint32_t u = __float_as_uint(f);
  u += 0x7fffu + ((u >> 16) & 1u);
  return (uint16_t)(u >> 16);
}

// ---------------------------------------------------------------------------
// Kernel 0: canonicalize Q_len / V_len. The reference declares int64 but jax
// usually canonicalizes to int32; detect at runtime: if all odd int32 words of
// the first 32 are zero -> int64 layout (values < 512 so high words are 0).
// lens[0..31] = Q_len, lens[32..63] = V_len.
// ---------------------------------------------------------------------------
__global__ void lens_kernel(const int* __restrict__ qlen_raw,
                            const int* __restrict__ vlen_raw,
                            int* __restrict__ lens) {
  __shared__ int is64[2];
  int t = threadIdx.x;
  if (t < 2) {
    const int* src = (t == 0) ? qlen_raw : vlen_raw;
    int o = 0;
    for (int i = 0; i < 16; ++i) o |= src[2 * i + 1];
    is64[t] = (o == 0) ? 1 : 0;
  }
  __syncthreads();
  int which = t >> 5;   // 0 -> qlen, 1 -> vlen
  int i = t & 31;
  const int* src = which ? vlen_raw : qlen_raw;
  lens[t] = is64[which] ? src[2 * i] : src[i];
}

// ---------------------------------------------------------------------------
// Kernel 1: projections. C = X @ W, X:(16384,768) W:(768,768), fp32 in,
// bf16 out scattered to head-major layout [B][H][L][DH].
// blockIdx.z selects (Q,K,V). 128x128 tile, BK=8, 8x8 micro-tile, 256 thr.
// ---------------------------------------------------------------------------
#define PBM 128
#define PBN 128
#define PBK 8

__global__ __launch_bounds__(256) void proj_kernel(
    const float* __restrict__ Xq, const float* __restrict__ Xk,
    const float* __restrict__ Xv, const float* __restrict__ Wq,
    const float* __restrict__ Wk, const float* __restrict__ Wv,
    uint16_t* __restrict__ qh, uint16_t* __restrict__ kh,
    uint16_t* __restrict__ vh) {
  const float* X;
  const float* W;
  uint16_t* dst;
  int z = blockIdx.z;
  if (z == 0)      { X = Xq; W = Wq; dst = qh; }
  else if (z == 1) { X = Xk; W = Wk; dst = kh; }
  else             { X = Xv; W = Wv; dst = vh; }

  __shared__ float Xs[PBK][PBM];   // [k][m]
  __shared__ float Ws_[PBK][PBN];  // [k][n]

  const int t  = threadIdx.x;
  const int r0 = blockIdx.x * PBM;
  const int c0 = blockIdx.y * PBN;
  const int tx = t & 15;   // n group
  const int ty = t >> 4;   // m group

  float acc[8][8];
#pragma unroll
  for (int i = 0; i < 8; ++i)
#pragma unroll
    for (int j = 0; j < 8; ++j) acc[i][j] = 0.0f;

  const int xr  = t >> 1;          // 0..127 row within tile
  const int xk4 = (t & 1) * 4;     // 0 or 4
  const int wr  = t >> 5;          // 0..7 k row
  const int wc4 = (t & 31) * 4;    // 0..124

  const float* Xbase = X + (size_t)(r0 + xr) * DIN_;
  const float* Wbase = W + c0 + wc4;

  for (int kt = 0; kt < DIN_ / PBK; ++kt) {
    const int k0 = kt * PBK;
    float4 xv4 = *(const float4*)(Xbase + k0 + xk4);
    float4 wv4 = *(const float4*)(Wbase + (size_t)(k0 + wr) * DOUT_);
    __syncthreads();   // previous iteration finished reading LDS
    Xs[xk4 + 0][xr] = xv4.x;
    Xs[xk4 + 1][xr] = xv4.y;
    Xs[xk4 + 2][xr] = xv4.z;
    Xs[xk4 + 3][xr] = xv4.w;
    *(float4*)&Ws_[wr][wc4] = wv4;
    __syncthreads();
#pragma unroll
    for (int kk = 0; kk < PBK; ++kk) {
      float a[8], b[8];
      *(float4*)&a[0] = *(const float4*)&Xs[kk][ty * 8];
      *(float4*)&a[4] = *(const float4*)&Xs[kk][ty * 8 + 4];
      *(float4*)&b[0] = *(const float4*)&Ws_[kk][tx * 8];
      *(float4*)&b[4] = *(const float4*)&Ws_[kk][tx * 8 + 4];
#pragma unroll
      for (int i = 0; i < 8; ++i)
#pragma unroll
        for (int j = 0; j < 8; ++j)
          acc[i][j] = fmaf(a[i], b[j], acc[i][j]);
    }
  }

  // epilogue: scatter to [B][H][L][DH] bf16
#pragma unroll
  for (int i = 0; i < 8; ++i) {
    const int r  = r0 + ty * 8 + i;
    const int bb = r >> 9;       // / 512
    const int l  = r & 511;
#pragma unroll
    for (int j = 0; j < 8; ++j) {
      const int c = c0 + tx * 8 + j;
      const int h = c / DH_;
      const int d = c - h * DH_;
      dst[((size_t)(bb * H_ + h) * L_ + l) * DH_ + d] = f2bf(acc[i][j]);
    }
  }
}

// ---------------------------------------------------------------------------
// Kernel 2: fused attention per (b,h). Single pass over q-groups of 4:
//   A) S[4][512] = Q K^T * scale - masks (exact reference arithmetic)
//   B) per-row softmax stats + normalized p written back to LDS
//   C) O[k][d] += p[q][k] * v[q][d]  (the reference's A^T V quirk)
// Output with Q_len row mask, fp32.
// LDS: Ks bf16 [512][52] (stride 52 -> 8B-aligned b64 rows, bank-spread)
//      + Ps fp32 [4][512] + Qb fp32 [4][48] = 62208 B < 64KB -> 2 blocks/CU,
//      all 512 blocks resident.
// ---------------------------------------------------------------------------
__global__ __launch_bounds__(256, 2) void attn_kernel(
    const uint16_t* __restrict__ qh, const uint16_t* __restrict__ kh,
    const uint16_t* __restrict__ vh, const int* __restrict__ lens,
    float* __restrict__ out) {
  const int bh = blockIdx.x;
  const int b  = bh >> 4;
  const int h  = bh & 15;
  const int t    = threadIdx.x;
  const int w    = t >> 6;    // wave 0..3
  const int lane = t & 63;

  const int qlen = lens[b];
  const int vlen = lens[32 + b];

  __shared__ uint16_t Ks[512][52];  // 53248 B (48 used + 4 pad)
  __shared__ float    Ps[4][512];   //  8192 B
  __shared__ float    Qb[4][48];    //   768 B

  const size_t headoff = (size_t)bh * HEADELEMS;

  // stage K head: 24576 bf16 = 6144 uint2 (4 bf16 each)
  {
    const uint2* src = (const uint2*)(kh + headoff);
    for (int i = t; i < 6144; i += 256) {
      uint2 v = src[i];
      int row = i / 12;          // 12 quads per 48-elem row
      int c4  = i - row * 12;
      *(uint2*)&Ks[row][c4 * 4] = v;   // byte off = row*104 + c4*8, 8B aligned
    }
  }
  __syncthreads();

  // per-lane output ownership: 8 k-rows x 12 dims
  const int kg    = lane >> 2;            // 0..15
  const int dg    = lane & 3;             // 0..3
  const int kbase = w * 128 + kg * 8;
  const int dbase = dg * 12;

  float acc[8][12];
#pragma unroll
  for (int i = 0; i < 8; ++i)
#pragma unroll
    for (int j = 0; j < 12; ++j) acc[i][j] = 0.0f;

  const int k1 = t;         // phase-A k assignments
  const int k2 = t + 256;
  const float scale = 0.14433756729740643f;  // 1/sqrt(48)

  for (int g = 0; g < 128; ++g) {
    const int q0 = g * 4;

    // stage 4 q rows (192 bf16 = 96 u32)
    if (t < 96) {
      int row = t / 24;
      int p   = t - row * 24;
      uint32_t u = *(const uint32_t*)(qh + headoff + (size_t)(q0 + row) * DH_ + p * 2);
      Qb[row][p * 2]     = __uint_as_float(u << 16);
      Qb[row][p * 2 + 1] = __uint_as_float(u & 0xffff0000u);
    }
    __syncthreads();

    // Phase A: dots, 4 q x 2 k per thread
    float sacc[4][2];
#pragma unroll
    for (int qq = 0; qq < 4; ++qq) { sacc[qq][0] = 0.f; sacc[qq][1] = 0.f; }
#pragma unroll
    for (int c = 0; c < 12; ++c) {
      float qv[4][4];
#pragma unroll
      for (int qq = 0; qq < 4; ++qq)
        *(float4*)qv[qq] = *(const float4*)&Qb[qq][c * 4];
      float kv[2][4];
#pragma unroll
      for (int kk = 0; kk < 2; ++kk) {
        const int k = (kk == 0) ? k1 : k2;
        uint2 u = *(const uint2*)&Ks[k][c * 4];
        kv[kk][0] = __uint_as_float(u.x << 16);
        kv[kk][1] = __uint_as_float(u.x & 0xffff0000u);
        kv[kk][2] = __uint_as_float(u.y << 16);
        kv[kk][3] = __uint_as_float(u.y & 0xffff0000u);
      }
#pragma unroll
      for (int qq = 0; qq < 4; ++qq)
#pragma unroll
        for (int kk = 0; kk < 2; ++kk)
#pragma unroll
          for (int d = 0; d < 4; ++d)
            sacc[qq][kk] = fmaf(qv[qq][d], kv[kk][d], sacc[qq][kk]);
    }
#pragma unroll
    for (int qq = 0; qq < 4; ++qq)
#pragma unroll
      for (int kk = 0; kk < 2; ++kk) {
        const int k = (kk == 0) ? k1 : k2;
        float s = sacc[qq][kk] * scale;
        if (k >= vlen)    s -= 1e12f;   // key-length mask (exactly -1e12: |s| absorbed)
        if (k > q0 + qq)  s -= 1e12f;   // causal mask
        Ps[qq][k] = s;
      }
    __syncthreads();

    // Phase B: softmax stats, one row per wave; write normalized p back
    {
      const int qq = w;
      float sv[8];
#pragma unroll
      for (int j = 0; j < 8; ++j) sv[j] = Ps[qq][lane + 64 * j];
      float m = sv[0];
#pragma unroll
      for (int j = 1; j < 8; ++j) m = fmaxf(m, sv[j]);
#pragma unroll
      for (int off = 32; off >= 1; off >>= 1)
        m = fmaxf(m, __shfl_xor(m, off, 64));
      float e[8];
      float l = 0.0f;
#pragma unroll
      for (int j = 0; j < 8; ++j) { e[j] = __expf(sv[j] - m); l += e[j]; }
#pragma unroll
      for (int off = 32; off >= 1; off >>= 1)
        l += __shfl_xor(l, off, 64);
      const float rl = 1.0f / l;   // l >= 1 always (max entry contributes 1)
#pragma unroll
      for (int j = 0; j < 8; ++j) Ps[qq][lane + 64 * j] = e[j] * rl;
    }
    __syncthreads();

    // Phase C: O[k][d] += p[q][k] * v[q][d]
#pragma unroll
    for (int qq = 0; qq < 4; ++qq) {
      const int q = q0 + qq;
      float pv[8];
      *(float4*)&pv[0] = *(const float4*)&Ps[qq][kbase];
      *(float4*)&pv[4] = *(const float4*)&Ps[qq][kbase + 4];
      float vv[12];
      const uint16_t* vrow = vh + headoff + (size_t)q * DH_ + dbase;
#pragma unroll
      for (int c = 0; c < 3; ++c) {
        uint2 u = *(const uint2*)(vrow + c * 4);
        vv[c * 4 + 0] = __uint_as_float(u.x << 16);
        vv[c * 4 + 1] = __uint_as_float(u.x & 0xffff0000u);
        vv[c * 4 + 2] = __uint_as_float(u.y << 16);
        vv[c * 4 + 3] = __uint_as_float(u.y & 0xffff0000u);
      }
#pragma unroll
      for (int i = 0; i < 8; ++i)
#pragma unroll
        for (int j = 0; j < 12; ++j)
          acc[i][j] = fmaf(pv[i], vv[j], acc[i][j]);
    }
    __syncthreads();  // Ps/Qb reused next group
  }

  // epilogue: Q_len row mask, write fp32 out [B][L][H*DH]
#pragma unroll
  for (int i = 0; i < 8; ++i) {
    const int krow = kbase + i;
    const float msk = (krow < qlen) ? 1.0f : 0.0f;
    float* orow = out + (size_t)(b * L_ + krow) * DOUT_ + h * DH_ + dbase;
#pragma unroll
    for (int c = 0; c < 3; ++c) {
      float4 v4;
      v4.x = acc[i][c * 4 + 0] * msk;
      v4.y = acc[i][c * 4 + 1] * msk;
      v4.z = acc[i][c * 4 + 2] * msk;
      v4.w = acc[i][c * 4 + 3] * msk;
      *(float4*)(orow + c * 4) = v4;
    }
  }
}

// ---------------------------------------------------------------------------
// launch
// ws layout: [0,256)  lens (64 ints)
//            [256, +25165824)          qh bf16 [B][H][L][DH]
//            [+25165824, +50331648)    kh
//            [+50331648, +75497472)    vh      (total ~75.5 MB)
// ---------------------------------------------------------------------------
extern "C" void kernel_launch(void* const* d_in, const int* in_sizes, int n_in,
                              void* d_out, int out_size, void* d_ws, size_t ws_size,
                              hipStream_t stream) {
  const float* Qs  = (const float*)d_in[0];
  const float* Kse = (const float*)d_in[1];
  const float* Vs  = (const float*)d_in[2];
  const float* WQ  = (const float*)d_in[3];
  const float* WK  = (const float*)d_in[4];
  const float* WV  = (const float*)d_in[5];
  const int*   Qlen = (const int*)d_in[6];
  const int*   Vlen = (const int*)d_in[7];
  float* out = (float*)d_out;

  char* ws = (char*)d_ws;
  int* lens = (int*)ws;
  uint16_t* qh = (uint16_t*)(ws + 256);
  uint16_t* kh = qh + (size_t)B_ * H_ * L_ * DH_;
  uint16_t* vh = kh + (size_t)B_ * H_ * L_ * DH_;

  lens_kernel<<<1, 64, 0, stream>>>(Qlen, Vlen, lens);
  proj_kernel<<<dim3(16384 / PBM, DOUT_ / PBN, 3), 256, 0, stream>>>(
      Qs, Kse, Vs, WQ, WK, WV, qh, kh, vh);
  attn_kernel<<<NHEADS, 256, 0, stream>>>(qh, kh, vh, lens, out);
}

// Round 2
// 794.077 us; speedup vs baseline: 1.7084x; 1.7084x over previous
//
#include <hip/hip_runtime.h>
#include <stdint.h>

// Problem constants
#define B_    32
#define L_    512
#define DIN_  768
#define H_    16
#define DH_   48
#define DOUT_ 768
#define NHEADS (B_ * H_)          // 512
#define HEADELEMS (L_ * DH_)      // 24576 elems per head

typedef short bf16x8 __attribute__((ext_vector_type(8)));  // 8 bf16 (4 VGPRs)
typedef float f32x4  __attribute__((ext_vector_type(4)));  // MFMA accumulator

// ---------------------------------------------------------------------------
// bf16 helpers (manual RNE — bit-identical to round-1 path)
// ---------------------------------------------------------------------------
__device__ __forceinline__ uint16_t f2bf(float f) {
  uint32_t u = __float_as_uint(f);
  u += 0x7fffu + ((u >> 16) & 1u);
  return (uint16_t)(u >> 16);
}
__device__ __forceinline__ uint32_t pack2bf(float lo, float hi) {
  uint32_t a = __float_as_uint(lo);
  a += 0x7fffu + ((a >> 16) & 1u);
  uint32_t b = __float_as_uint(hi);
  b += 0x7fffu + ((b >> 16) & 1u);
  return (a >> 16) | (b & 0xffff0000u);
}
// async global->LDS, 16B per lane (wave-uniform base + lane*16 layout)
__device__ __forceinline__ void gload_lds16(const void* g, void* l) {
  __builtin_amdgcn_global_load_lds(
      (const __attribute__((address_space(1))) uint32_t*)g,
      (__attribute__((address_space(3))) uint32_t*)l, 16, 0, 0);
}

// ---------------------------------------------------------------------------
// Kernel 0: canonicalize Q_len / V_len (int64-vs-int32 autodetect).
// lens[0..31] = Q_len, lens[32..63] = V_len.
// ---------------------------------------------------------------------------
__global__ void lens_kernel(const int* __restrict__ qlen_raw,
                            const int* __restrict__ vlen_raw,
                            int* __restrict__ lens) {
  __shared__ int is64[2];
  int t = threadIdx.x;
  if (t < 2) {
    const int* src = (t == 0) ? qlen_raw : vlen_raw;
    int o = 0;
    for (int i = 0; i < 16; ++i) o |= src[2 * i + 1];
    is64[t] = (o == 0) ? 1 : 0;
  }
  __syncthreads();
  int which = t >> 5;
  int i = t & 31;
  const int* src = which ? vlen_raw : qlen_raw;
  lens[t] = is64[which] ? src[2 * i] : src[i];
}

// ---------------------------------------------------------------------------
// Kernel 1: W transpose+convert.  Wt[z][n][k] = bf16(W_z[k][n]).
// grid (3, 192, 3), block 256.  Reads coalesced; tiny (1.8 MB/z), L2-resident.
// ---------------------------------------------------------------------------
__global__ void wconv_kernel(const float* __restrict__ WQ,
                             const float* __restrict__ WK,
                             const float* __restrict__ WV,
                             uint16_t* __restrict__ Wt) {
  const int z = blockIdx.z;
  const float* W = (z == 0) ? WQ : (z == 1) ? WK : WV;
  uint16_t* dst = Wt + (size_t)z * DIN_ * DOUT_;
  const int n  = blockIdx.x * 256 + threadIdx.x;   // 0..767
  const int k4 = blockIdx.y * 4;                   // 0..764
  float f0 = W[(size_t)(k4 + 0) * DOUT_ + n];
  float f1 = W[(size_t)(k4 + 1) * DOUT_ + n];
  float f2 = W[(size_t)(k4 + 2) * DOUT_ + n];
  float f3 = W[(size_t)(k4 + 3) * DOUT_ + n];
  uint2 p;
  p.x = pack2bf(f0, f1);
  p.y = pack2bf(f2, f3);
  *(uint2*)&dst[(size_t)n * DIN_ + k4] = p;
}

// ---------------------------------------------------------------------------
// Kernel 2: MFMA projection GEMM.  C = X @ W, X:(16384,768) fp32,
// Wt:(768n,768k) bf16.  128x128 tile, BK=32, 4 waves x (4x4 of 16x16x32).
// A staged via VGPR (fp32 load + RNE pack to bf16), B via global_load_lds x16.
// Output bf16 scattered to head-major [B][H][L][DH].
// ---------------------------------------------------------------------------
__global__ __launch_bounds__(256) void mfma_proj(
    const float* __restrict__ Xq, const float* __restrict__ Xk,
    const float* __restrict__ Xv, const uint16_t* __restrict__ Wt,
    uint16_t* __restrict__ qh, uint16_t* __restrict__ kh,
    uint16_t* __restrict__ vh) {
  const int z = blockIdx.z;
  const float* X = (z == 0) ? Xq : (z == 1) ? Xk : Xv;
  uint16_t* dst  = (z == 0) ? qh : (z == 1) ? kh : vh;
  const uint16_t* W = Wt + (size_t)z * DIN_ * DOUT_;   // [n][k] bf16

  __shared__ uint16_t As[128][32];   // [m][k] 8 KB
  __shared__ uint16_t Bs[128][32];   // [n][k] 8 KB

  const int t  = threadIdx.x;
  const int m0 = blockIdx.x * 128;
  const int n0 = blockIdx.y * 128;

  // A staging: thread owns row ra = t>>1, 16 consecutive k at ca
  const int ra = t >> 1;
  const int ca = (t & 1) * 16;
  const float* aptr = X + (size_t)(m0 + ra) * DIN_ + ca;

  // B staging: two 16B chunks per thread, LDS-linear (lane-order) layout
  const uint16_t* bptr0 = W + (size_t)(n0 + (t >> 2)) * DIN_ + (t & 3) * 8;
  const uint16_t* bptr1 = bptr0 + (size_t)64 * DIN_;
  void* ldsB0 = (char*)(&Bs[0][0]) + t * 16;
  void* ldsB1 = (char*)ldsB0 + 4096;

  const int w = t >> 6, lane = t & 63;
  const int wm = (w & 1) * 64, wn = (w >> 1) * 64;
  const int fr = lane & 15;      // m (A) / n (B) / col (D)
  const int quad = lane >> 4;    // k group (A/B) / row group (D)

  f32x4 acc[4][4];
#pragma unroll
  for (int i = 0; i < 4; ++i)
#pragma unroll
    for (int j = 0; j < 4; ++j) acc[i][j] = f32x4{0.f, 0.f, 0.f, 0.f};

  for (int kt = 0; kt < DIN_ / 32; ++kt) {
    const int k0 = kt * 32;
    // B: async direct-to-LDS
    gload_lds16(bptr0 + k0, ldsB0);
    gload_lds16(bptr1 + k0, ldsB1);
    // A: fp32 load -> bf16 pack -> LDS
    float4 x0 = *(const float4*)(aptr + k0);
    float4 x1 = *(const float4*)(aptr + k0 + 4);
    float4 x2 = *(const float4*)(aptr + k0 + 8);
    float4 x3 = *(const float4*)(aptr + k0 + 12);
    uint4 pA, pB;
    pA.x = pack2bf(x0.x, x0.y); pA.y = pack2bf(x0.z, x0.w);
    pA.z = pack2bf(x1.x, x1.y); pA.w = pack2bf(x1.z, x1.w);
    pB.x = pack2bf(x2.x, x2.y); pB.y = pack2bf(x2.z, x2.w);
    pB.z = pack2bf(x3.x, x3.y); pB.w = pack2bf(x3.z, x3.w);
    *(uint4*)&As[ra][ca]     = pA;
    *(uint4*)&As[ra][ca + 8] = pB;
    __syncthreads();   // drains vmcnt (B in LDS) + lgkm (A writes)

    bf16x8 af[4], bfr[4];
#pragma unroll
    for (int i = 0; i < 4; ++i) {
      af[i]  = *(const bf16x8*)&As[wm + i * 16 + fr][quad * 8];
      bfr[i] = *(const bf16x8*)&Bs[wn + i * 16 + fr][quad * 8];
    }
#pragma unroll
    for (int mt = 0; mt < 4; ++mt)
#pragma unroll
      for (int nt = 0; nt < 4; ++nt)
        acc[mt][nt] = __builtin_amdgcn_mfma_f32_16x16x32_bf16(
            af[mt], bfr[nt], acc[mt][nt], 0, 0, 0);
    __syncthreads();   // LDS safe to overwrite next iter
  }

  // epilogue: D[row=quad*4+r][col=fr] -> head-major bf16
#pragma unroll
  for (int mt = 0; mt < 4; ++mt) {
#pragma unroll
    for (int r = 0; r < 4; ++r) {
      const int m  = m0 + wm + mt * 16 + quad * 4 + r;
      const int bb = m >> 9;
      const int l  = m & 511;
#pragma unroll
      for (int nt = 0; nt < 4; ++nt) {
        const int n = n0 + wn + nt * 16 + fr;
        const int h = n / DH_;
        const int d = n - h * DH_;
        dst[(((size_t)bb * H_ + h) * L_ + l) * DH_ + d] = f2bf(acc[mt][nt][r]);
      }
    }
  }
}

// ---------------------------------------------------------------------------
// Kernel 3: fused attention per (b,h) — unchanged from round 1.
// ---------------------------------------------------------------------------
__global__ __launch_bounds__(256, 2) void attn_kernel(
    const uint16_t* __restrict__ qh, const uint16_t* __restrict__ kh,
    const uint16_t* __restrict__ vh, const int* __restrict__ lens,
    float* __restrict__ out) {
  const int bh = blockIdx.x;
  const int b  = bh >> 4;
  const int h  = bh & 15;
  const int t    = threadIdx.x;
  const int w    = t >> 6;
  const int lane = t & 63;

  const int qlen = lens[b];
  const int vlen = lens[32 + b];

  __shared__ uint16_t Ks[512][52];
  __shared__ float    Ps[4][512];
  __shared__ float    Qb[4][48];

  const size_t headoff = (size_t)bh * HEADELEMS;

  {
    const uint2* src = (const uint2*)(kh + headoff);
    for (int i = t; i < 6144; i += 256) {
      uint2 v = src[i];
      int row = i / 12;
      int c4  = i - row * 12;
      *(uint2*)&Ks[row][c4 * 4] = v;
    }
  }
  __syncthreads();

  const int kg    = lane >> 2;
  const int dg    = lane & 3;
  const int kbase = w * 128 + kg * 8;
  const int dbase = dg * 12;

  float acc[8][12];
#pragma unroll
  for (int i = 0; i < 8; ++i)
#pragma unroll
    for (int j = 0; j < 12; ++j) acc[i][j] = 0.0f;

  const int k1 = t;
  const int k2 = t + 256;
  const float scale = 0.14433756729740643f;  // 1/sqrt(48)

  for (int g = 0; g < 128; ++g) {
    const int q0 = g * 4;

    if (t < 96) {
      int row = t / 24;
      int p   = t - row * 24;
      uint32_t u = *(const uint32_t*)(qh + headoff + (size_t)(q0 + row) * DH_ + p * 2);
      Qb[row][p * 2]     = __uint_as_float(u << 16);
      Qb[row][p * 2 + 1] = __uint_as_float(u & 0xffff0000u);
    }
    __syncthreads();

    float sacc[4][2];
#pragma unroll
    for (int qq = 0; qq < 4; ++qq) { sacc[qq][0] = 0.f; sacc[qq][1] = 0.f; }
#pragma unroll
    for (int c = 0; c < 12; ++c) {
      float qv[4][4];
#pragma unroll
      for (int qq = 0; qq < 4; ++qq)
        *(float4*)qv[qq] = *(const float4*)&Qb[qq][c * 4];
      float kv[2][4];
#pragma unroll
      for (int kk = 0; kk < 2; ++kk) {
        const int k = (kk == 0) ? k1 : k2;
        uint2 u = *(const uint2*)&Ks[k][c * 4];
        kv[kk][0] = __uint_as_float(u.x << 16);
        kv[kk][1] = __uint_as_float(u.x & 0xffff0000u);
        kv[kk][2] = __uint_as_float(u.y << 16);
        kv[kk][3] = __uint_as_float(u.y & 0xffff0000u);
      }
#pragma unroll
      for (int qq = 0; qq < 4; ++qq)
#pragma unroll
        for (int kk = 0; kk < 2; ++kk)
#pragma unroll
          for (int d = 0; d < 4; ++d)
            sacc[qq][kk] = fmaf(qv[qq][d], kv[kk][d], sacc[qq][kk]);
    }
#pragma unroll
    for (int qq = 0; qq < 4; ++qq)
#pragma unroll
      for (int kk = 0; kk < 2; ++kk) {
        const int k = (kk == 0) ? k1 : k2;
        float s = sacc[qq][kk] * scale;
        if (k >= vlen)    s -= 1e12f;
        if (k > q0 + qq)  s -= 1e12f;
        Ps[qq][k] = s;
      }
    __syncthreads();

    {
      const int qq = w;
      float sv[8];
#pragma unroll
      for (int j = 0; j < 8; ++j) sv[j] = Ps[qq][lane + 64 * j];
      float m = sv[0];
#pragma unroll
      for (int j = 1; j < 8; ++j) m = fmaxf(m, sv[j]);
#pragma unroll
      for (int off = 32; off >= 1; off >>= 1)
        m = fmaxf(m, __shfl_xor(m, off, 64));
      float e[8];
      float l = 0.0f;
#pragma unroll
      for (int j = 0; j < 8; ++j) { e[j] = __expf(sv[j] - m); l += e[j]; }
#pragma unroll
      for (int off = 32; off >= 1; off >>= 1)
        l += __shfl_xor(l, off, 64);
      const float rl = 1.0f / l;
#pragma unroll
      for (int j = 0; j < 8; ++j) Ps[qq][lane + 64 * j] = e[j] * rl;
    }
    __syncthreads();

#pragma unroll
    for (int qq = 0; qq < 4; ++qq) {
      const int q = q0 + qq;
      float pv[8];
      *(float4*)&pv[0] = *(const float4*)&Ps[qq][kbase];
      *(float4*)&pv[4] = *(const float4*)&Ps[qq][kbase + 4];
      float vv[12];
      const uint16_t* vrow = vh + headoff + (size_t)q * DH_ + dbase;
#pragma unroll
      for (int c = 0; c < 3; ++c) {
        uint2 u = *(const uint2*)(vrow + c * 4);
        vv[c * 4 + 0] = __uint_as_float(u.x << 16);
        vv[c * 4 + 1] = __uint_as_float(u.x & 0xffff0000u);
        vv[c * 4 + 2] = __uint_as_float(u.y << 16);
        vv[c * 4 + 3] = __uint_as_float(u.y & 0xffff0000u);
      }
#pragma unroll
      for (int i = 0; i < 8; ++i)
#pragma unroll
        for (int j = 0; j < 12; ++j)
          acc[i][j] = fmaf(pv[i], vv[j], acc[i][j]);
    }
    __syncthreads();
  }

#pragma unroll
  for (int i = 0; i < 8; ++i) {
    const int krow = kbase + i;
    const float msk = (krow < qlen) ? 1.0f : 0.0f;
    float* orow = out + (size_t)(b * L_ + krow) * DOUT_ + h * DH_ + dbase;
#pragma unroll
    for (int c = 0; c < 3; ++c) {
      float4 v4;
      v4.x = acc[i][c * 4 + 0] * msk;
      v4.y = acc[i][c * 4 + 1] * msk;
      v4.z = acc[i][c * 4 + 2] * msk;
      v4.w = acc[i][c * 4 + 3] * msk;
      *(float4*)(orow + c * 4) = v4;
    }
  }
}

// ---------------------------------------------------------------------------
// launch
// ws layout: [0,256)        lens (64 ints)
//            [256, +75.5MB) qh/kh/vh bf16 [B][H][L][DH] x3
//            [+75.5MB, +3.5MB) Wt bf16 [3][768][768]
// ---------------------------------------------------------------------------
extern "C" void kernel_launch(void* const* d_in, const int* in_sizes, int n_in,
                              void* d_out, int out_size, void* d_ws, size_t ws_size,
                              hipStream_t stream) {
  const float* Qs  = (const float*)d_in[0];
  const float* Kse = (const float*)d_in[1];
  const float* Vs  = (const float*)d_in[2];
  const float* WQ  = (const float*)d_in[3];
  const float* WK  = (const float*)d_in[4];
  const float* WV  = (const float*)d_in[5];
  const int*   Qlen = (const int*)d_in[6];
  const int*   Vlen = (const int*)d_in[7];
  float* out = (float*)d_out;

  char* ws = (char*)d_ws;
  int* lens = (int*)ws;
  uint16_t* qh = (uint16_t*)(ws + 256);
  uint16_t* kh = qh + (size_t)B_ * H_ * L_ * DH_;
  uint16_t* vh = kh + (size_t)B_ * H_ * L_ * DH_;
  uint16_t* Wt = vh + (size_t)B_ * H_ * L_ * DH_;

  lens_kernel<<<1, 64, 0, stream>>>(Qlen, Vlen, lens);
  wconv_kernel<<<dim3(3, 192, 3), 256, 0, stream>>>(WQ, WK, WV, Wt);
  mfma_proj<<<dim3(16384 / 128, DOUT_ / 128, 3), 256, 0, stream>>>(
      Qs, Kse, Vs, Wt, qh, kh, vh);
  attn_kernel<<<NHEADS, 256, 0, stream>>>(qh, kh, vh, lens, out);
}

// Round 3
// 436.906 us; speedup vs baseline: 3.1050x; 1.8175x over previous
//
#include <hip/hip_runtime.h>
#include <stdint.h>

// Problem constants
#define B_    32
#define L_    512
#define DIN_  768
#define H_    16
#define DH_   48
#define DOUT_ 768
#define NHEADS (B_ * H_)          // 512
#define HEADELEMS (L_ * DH_)      // 24576 elems per head

typedef short bf16x8 __attribute__((ext_vector_type(8)));  // 8 bf16 (4 VGPRs)
typedef float f32x4  __attribute__((ext_vector_type(4)));  // MFMA accumulator

// ---------------------------------------------------------------------------
// bf16 helpers (manual RNE)
// ---------------------------------------------------------------------------
__device__ __forceinline__ uint16_t f2bf(float f) {
  uint32_t u = __float_as_uint(f);
  u += 0x7fffu + ((u >> 16) & 1u);
  return (uint16_t)(u >> 16);
}
__device__ __forceinline__ uint32_t pack2bf(float lo, float hi) {
  uint32_t a = __float_as_uint(lo);
  a += 0x7fffu + ((a >> 16) & 1u);
  uint32_t b = __float_as_uint(hi);
  b += 0x7fffu + ((b >> 16) & 1u);
  return (a >> 16) | (b & 0xffff0000u);
}
// async global->LDS, 16B per lane
__device__ __forceinline__ void gload_lds16(const void* g, void* l) {
  __builtin_amdgcn_global_load_lds(
      (const __attribute__((address_space(1))) uint32_t*)g,
      (__attribute__((address_space(3))) uint32_t*)l, 16, 0, 0);
}
// bf16x8 fragment from LDS at 8B-aligned address (two ds_read_b64)
__device__ __forceinline__ bf16x8 lds_frag8(const uint16_t* p) {
  union { uint2 u[2]; bf16x8 v; } x;
  x.u[0] = *(const uint2*)(p);
  x.u[1] = *(const uint2*)(p + 4);
  return x.v;
}

// ---------------------------------------------------------------------------
// Kernel 0: canonicalize Q_len / V_len (int64-vs-int32 autodetect).
// ---------------------------------------------------------------------------
__global__ void lens_kernel(const int* __restrict__ qlen_raw,
                            const int* __restrict__ vlen_raw,
                            int* __restrict__ lens) {
  __shared__ int is64[2];
  int t = threadIdx.x;
  if (t < 2) {
    const int* src = (t == 0) ? qlen_raw : vlen_raw;
    int o = 0;
    for (int i = 0; i < 16; ++i) o |= src[2 * i + 1];
    is64[t] = (o == 0) ? 1 : 0;
  }
  __syncthreads();
  int which = t >> 5;
  int i = t & 31;
  const int* src = which ? vlen_raw : qlen_raw;
  lens[t] = is64[which] ? src[2 * i] : src[i];
}

// ---------------------------------------------------------------------------
// Kernel 1: W transpose+convert.  Wt[z][n][k] = bf16(W_z[k][n]).
// ---------------------------------------------------------------------------
__global__ void wconv_kernel(const float* __restrict__ WQ,
                             const float* __restrict__ WK,
                             const float* __restrict__ WV,
                             uint16_t* __restrict__ Wt) {
  const int z = blockIdx.z;
  const float* W = (z == 0) ? WQ : (z == 1) ? WK : WV;
  uint16_t* dst = Wt + (size_t)z * DIN_ * DOUT_;
  const int n  = blockIdx.x * 256 + threadIdx.x;
  const int k4 = blockIdx.y * 4;
  float f0 = W[(size_t)(k4 + 0) * DOUT_ + n];
  float f1 = W[(size_t)(k4 + 1) * DOUT_ + n];
  float f2 = W[(size_t)(k4 + 2) * DOUT_ + n];
  float f3 = W[(size_t)(k4 + 3) * DOUT_ + n];
  uint2 p;
  p.x = pack2bf(f0, f1);
  p.y = pack2bf(f2, f3);
  *(uint2*)&dst[(size_t)n * DIN_ + k4] = p;
}

// ---------------------------------------------------------------------------
// Kernel 2: MFMA projection GEMM (unchanged from round 2; verified).
// ---------------------------------------------------------------------------
__global__ __launch_bounds__(256) void mfma_proj(
    const float* __restrict__ Xq, const float* __restrict__ Xk,
    const float* __restrict__ Xv, const uint16_t* __restrict__ Wt,
    uint16_t* __restrict__ qh, uint16_t* __restrict__ kh,
    uint16_t* __restrict__ vh) {
  const int z = blockIdx.z;
  const float* X = (z == 0) ? Xq : (z == 1) ? Xk : Xv;
  uint16_t* dst  = (z == 0) ? qh : (z == 1) ? kh : vh;
  const uint16_t* W = Wt + (size_t)z * DIN_ * DOUT_;

  __shared__ uint16_t As[128][32];
  __shared__ uint16_t Bs[128][32];

  const int t  = threadIdx.x;
  const int m0 = blockIdx.x * 128;
  const int n0 = blockIdx.y * 128;

  const int ra = t >> 1;
  const int ca = (t & 1) * 16;
  const float* aptr = X + (size_t)(m0 + ra) * DIN_ + ca;

  const uint16_t* bptr0 = W + (size_t)(n0 + (t >> 2)) * DIN_ + (t & 3) * 8;
  const uint16_t* bptr1 = bptr0 + (size_t)64 * DIN_;
  void* ldsB0 = (char*)(&Bs[0][0]) + t * 16;
  void* ldsB1 = (char*)ldsB0 + 4096;

  const int w = t >> 6, lane = t & 63;
  const int wm = (w & 1) * 64, wn = (w >> 1) * 64;
  const int fr = lane & 15;
  const int quad = lane >> 4;

  f32x4 acc[4][4];
#pragma unroll
  for (int i = 0; i < 4; ++i)
#pragma unroll
    for (int j = 0; j < 4; ++j) acc[i][j] = f32x4{0.f, 0.f, 0.f, 0.f};

  for (int kt = 0; kt < DIN_ / 32; ++kt) {
    const int k0 = kt * 32;
    gload_lds16(bptr0 + k0, ldsB0);
    gload_lds16(bptr1 + k0, ldsB1);
    float4 x0 = *(const float4*)(aptr + k0);
    float4 x1 = *(const float4*)(aptr + k0 + 4);
    float4 x2 = *(const float4*)(aptr + k0 + 8);
    float4 x3 = *(const float4*)(aptr + k0 + 12);
    uint4 pA, pB;
    pA.x = pack2bf(x0.x, x0.y); pA.y = pack2bf(x0.z, x0.w);
    pA.z = pack2bf(x1.x, x1.y); pA.w = pack2bf(x1.z, x1.w);
    pB.x = pack2bf(x2.x, x2.y); pB.y = pack2bf(x2.z, x2.w);
    pB.z = pack2bf(x3.x, x3.y); pB.w = pack2bf(x3.z, x3.w);
    *(uint4*)&As[ra][ca]     = pA;
    *(uint4*)&As[ra][ca + 8] = pB;
    __syncthreads();

    bf16x8 af[4], bfr[4];
#pragma unroll
    for (int i = 0; i < 4; ++i) {
      af[i]  = *(const bf16x8*)&As[wm + i * 16 + fr][quad * 8];
      bfr[i] = *(const bf16x8*)&Bs[wn + i * 16 + fr][quad * 8];
    }
#pragma unroll
    for (int mt = 0; mt < 4; ++mt)
#pragma unroll
      for (int nt = 0; nt < 4; ++nt)
        acc[mt][nt] = __builtin_amdgcn_mfma_f32_16x16x32_bf16(
            af[mt], bfr[nt], acc[mt][nt], 0, 0, 0);
    __syncthreads();
  }

#pragma unroll
  for (int mt = 0; mt < 4; ++mt) {
#pragma unroll
    for (int r = 0; r < 4; ++r) {
      const int m  = m0 + wm + mt * 16 + quad * 4 + r;
      const int bb = m >> 9;
      const int l  = m & 511;
#pragma unroll
      for (int nt = 0; nt < 4; ++nt) {
        const int n = n0 + wn + nt * 16 + fr;
        const int h = n / DH_;
        const int d = n - h * DH_;
        dst[(((size_t)bb * H_ + h) * L_ + l) * DH_ + d] = f2bf(acc[mt][nt][r]);
      }
    }
  }
}

// ---------------------------------------------------------------------------
// Kernel 3: MFMA attention.  One block per (b,h), 4 waves, q-step = 32.
// Wave w owns interleaved k-tiles {4i+w}, i=0..7 (128 k columns) -> balanced
// causal skip.  S via mfma(Q,K) with frags loaded from global (L1-resident
// head).  Split softmax (per-wave partials -> combine).  O = P^T V via mfma
// with P round-tripped through LDS (Pt, A-layout) and V transposed per step
// (Vt).  O accumulates in registers across all 16 q-steps.
// ---------------------------------------------------------------------------
__global__ __launch_bounds__(256, 2) void attn_mfma(
    const uint16_t* __restrict__ qh, const uint16_t* __restrict__ kh,
    const uint16_t* __restrict__ vh, const int* __restrict__ lens,
    float* __restrict__ out) {
  const int bh = blockIdx.x;
  const int b  = bh >> 4;
  const int h  = bh & 15;
  const int t    = threadIdx.x;
  const int w    = t >> 6;
  const int lane = t & 63;
  const int l15  = lane & 15;
  const int quad = lane >> 4;

  const int qlen = lens[b];
  const int vlen = lens[32 + b];
  const size_t head = (size_t)bh * HEADELEMS;

  __shared__ uint16_t Pt[4][128][36];  // 36864 B  [wave][k_loc][q_loc]
  __shared__ uint16_t Vt[48][36];      //  3456 B  [d][q_loc]
  __shared__ float    prt[4][32][2];   //  1024 B  per-wave (max, expsum)
  __shared__ float    cmb[32][2];      //   256 B  (row max, 1/L)

  const uint16_t* qbase = qh + head;
  const uint16_t* kbase = kh + head;
  const uint16_t* vbase = vh + head;

  f32x4 Oacc[8][3];
#pragma unroll
  for (int i = 0; i < 8; ++i)
#pragma unroll
    for (int dt = 0; dt < 3; ++dt) Oacc[i][dt] = f32x4{0.f, 0.f, 0.f, 0.f};

  const float scale = 0.14433756729740643f;  // 1/sqrt(48)
  const int vq  = t & 31;        // Vt staging: q_loc
  const int vd4 = t >> 5;        // Vt staging: d-quad 0..7

  for (int g = 0; g < 16; ++g) {
    const int q0 = g * 32;
    const int lim = q0 + 31 - 16 * w;   // tile i active iff 64*i <= lim

    __syncthreads();   // prev-iter PV reads of Pt/Vt and cmb reads done

    // ---- stage Vt[d][q_loc] (transposed V tile) ----
    {
      uint2 u = *(const uint2*)(vbase + (size_t)(q0 + vq) * DH_ + vd4 * 4);
      Vt[vd4 * 4 + 0][vq] = (uint16_t)(u.x);
      Vt[vd4 * 4 + 1][vq] = (uint16_t)(u.x >> 16);
      Vt[vd4 * 4 + 2][vq] = (uint16_t)(u.y);
      Vt[vd4 * 4 + 3][vq] = (uint16_t)(u.y >> 16);
      if (t < 128) {
        int d4b = 8 + (t >> 5);
        uint2 v = *(const uint2*)(vbase + (size_t)(q0 + vq) * DH_ + d4b * 4);
        Vt[d4b * 4 + 0][vq] = (uint16_t)(v.x);
        Vt[d4b * 4 + 1][vq] = (uint16_t)(v.x >> 16);
        Vt[d4b * 4 + 2][vq] = (uint16_t)(v.y);
        Vt[d4b * 4 + 3][vq] = (uint16_t)(v.y >> 16);
      }
    }

    // ---- Q A-fragments (2 m-tiles x 2 K-steps), d 48..63 zero-padded ----
    bf16x8 aq[2][2];
#pragma unroll
    for (int mt = 0; mt < 2; ++mt) {
      const uint16_t* qp = qbase + (size_t)(q0 + mt * 16 + l15) * DH_;
      aq[mt][0] = *(const bf16x8*)(qp + quad * 8);
      bf16x8 z = {0, 0, 0, 0, 0, 0, 0, 0};
      aq[mt][1] = z;
      if (quad < 2) aq[mt][1] = *(const bf16x8*)(qp + 32 + quad * 8);
    }

    // ---- S MFMAs for active tiles ----
    f32x4 sacc[2][8];
#pragma unroll
    for (int i = 0; i < 8; ++i) {
      if (64 * i > lim) continue;   // wave-uniform causal skip
      const int kb = 64 * i + 16 * w;
      const uint16_t* kp = kbase + (size_t)(kb + l15) * DH_;
      bf16x8 bk0 = *(const bf16x8*)(kp + quad * 8);
      bf16x8 bk1 = {0, 0, 0, 0, 0, 0, 0, 0};
      if (quad < 2) bk1 = *(const bf16x8*)(kp + 32 + quad * 8);
      f32x4 z = {0.f, 0.f, 0.f, 0.f};
      f32x4 s0 = __builtin_amdgcn_mfma_f32_16x16x32_bf16(aq[0][0], bk0, z, 0, 0, 0);
      sacc[0][i] = __builtin_amdgcn_mfma_f32_16x16x32_bf16(aq[0][1], bk1, s0, 0, 0, 0);
      f32x4 s1 = __builtin_amdgcn_mfma_f32_16x16x32_bf16(aq[1][0], bk0, z, 0, 0, 0);
      sacc[1][i] = __builtin_amdgcn_mfma_f32_16x16x32_bf16(aq[1][1], bk1, s1, 0, 0, 0);
    }

    // ---- masks + per-lane row partial max ----
    float rmax[2][4];
#pragma unroll
    for (int mt = 0; mt < 2; ++mt)
#pragma unroll
      for (int r = 0; r < 4; ++r) rmax[mt][r] = -3.0e38f;
#pragma unroll
    for (int i = 0; i < 8; ++i) {
      if (64 * i > lim) continue;
      const int kc = 64 * i + 16 * w + l15;
      const float lm = (kc >= vlen) ? 1e12f : 0.0f;
#pragma unroll
      for (int mt = 0; mt < 2; ++mt)
#pragma unroll
        for (int r = 0; r < 4; ++r) {
          const int qrow = q0 + mt * 16 + quad * 4 + r;
          float s = sacc[mt][i][r] * scale - lm;   // -1e12 absorbs s exactly
          if (kc > qrow) s -= 1e12f;               // causal
          sacc[mt][i][r] = s;
          rmax[mt][r] = fmaxf(rmax[mt][r], s);
        }
    }
    // reduce max over the 16 lanes of the quad-row group
#pragma unroll
    for (int mt = 0; mt < 2; ++mt)
#pragma unroll
      for (int r = 0; r < 4; ++r) {
#pragma unroll
        for (int off = 1; off < 16; off <<= 1)
          rmax[mt][r] = fmaxf(rmax[mt][r], __shfl_xor(rmax[mt][r], off, 64));
      }

    // ---- e = exp(s - rmax), per-lane row partial sum ----
    float rsum[2][4];
#pragma unroll
    for (int mt = 0; mt < 2; ++mt)
#pragma unroll
      for (int r = 0; r < 4; ++r) rsum[mt][r] = 0.0f;
#pragma unroll
    for (int i = 0; i < 8; ++i) {
      if (64 * i > lim) continue;
#pragma unroll
      for (int mt = 0; mt < 2; ++mt)
#pragma unroll
        for (int r = 0; r < 4; ++r) {
          float e = __expf(sacc[mt][i][r] - rmax[mt][r]);
          sacc[mt][i][r] = e;
          rsum[mt][r] += e;
        }
    }
#pragma unroll
    for (int mt = 0; mt < 2; ++mt)
#pragma unroll
      for (int r = 0; r < 4; ++r) {
#pragma unroll
        for (int off = 1; off < 16; off <<= 1)
          rsum[mt][r] += __shfl_xor(rsum[mt][r], off, 64);
      }

    // ---- write per-wave partials ----
    if (l15 == 0) {
#pragma unroll
      for (int mt = 0; mt < 2; ++mt)
#pragma unroll
        for (int r = 0; r < 4; ++r) {
          const int ql = mt * 16 + quad * 4 + r;
          float2 pr; pr.x = rmax[mt][r]; pr.y = rsum[mt][r];
          *(float2*)&prt[w][ql][0] = pr;
        }
    }
    __syncthreads();

    // ---- combine (32 threads): global max + 1/L per row ----
    if (t < 32) {
      float2 p0 = *(const float2*)&prt[0][t][0];
      float2 p1 = *(const float2*)&prt[1][t][0];
      float2 p2 = *(const float2*)&prt[2][t][0];
      float2 p3 = *(const float2*)&prt[3][t][0];
      float m = fmaxf(fmaxf(p0.x, p1.x), fmaxf(p2.x, p3.x));
      float L = p0.y * __expf(p0.x - m) + p1.y * __expf(p1.x - m) +
                p2.y * __expf(p2.x - m) + p3.y * __expf(p3.x - m);
      float2 c; c.x = m; c.y = 1.0f / L;
      *(float2*)&cmb[t][0] = c;
    }
    __syncthreads();

    // ---- rescale, pack bf16, write Pt (active tiles only) ----
    float gf[2][4];
#pragma unroll
    for (int mt = 0; mt < 2; ++mt)
#pragma unroll
      for (int r = 0; r < 4; ++r) {
        const int ql = mt * 16 + quad * 4 + r;
        float2 c = *(const float2*)&cmb[ql][0];
        gf[mt][r] = __expf(rmax[mt][r] - c.x) * c.y;
      }
#pragma unroll
    for (int i = 0; i < 8; ++i) {
      if (64 * i > lim) continue;
      const int row = i * 16 + l15;
#pragma unroll
      for (int mt = 0; mt < 2; ++mt) {
        float p0 = sacc[mt][i][0] * gf[mt][0];
        float p1 = sacc[mt][i][1] * gf[mt][1];
        float p2 = sacc[mt][i][2] * gf[mt][2];
        float p3 = sacc[mt][i][3] * gf[mt][3];
        const int col = mt * 16 + quad * 4;
        *(uint32_t*)&Pt[w][row][col]     = pack2bf(p0, p1);
        *(uint32_t*)&Pt[w][row][col + 2] = pack2bf(p2, p3);
      }
    }
    __syncthreads();

    // ---- PV MFMAs: Oacc[k_loc][d] += P^T[k][q] V[q][d] ----
    bf16x8 bv[3];
#pragma unroll
    for (int dt = 0; dt < 3; ++dt)
      bv[dt] = lds_frag8(&Vt[dt * 16 + l15][quad * 8]);
#pragma unroll
    for (int i = 0; i < 8; ++i) {
      if (64 * i > lim) continue;
      bf16x8 ap = lds_frag8(&Pt[w][i * 16 + l15][quad * 8]);
#pragma unroll
      for (int dt = 0; dt < 3; ++dt)
        Oacc[i][dt] = __builtin_amdgcn_mfma_f32_16x16x32_bf16(
            ap, bv[dt], Oacc[i][dt], 0, 0, 0);
    }
  }

  // ---- epilogue: Q_len row mask, fp32 out [B][L][H*DH] ----
#pragma unroll
  for (int i = 0; i < 8; ++i) {
#pragma unroll
    for (int r = 0; r < 4; ++r) {
      const int k_abs = 64 * i + 16 * w + quad * 4 + r;
      const float msk = (k_abs < qlen) ? 1.0f : 0.0f;
      float* orow = out + (size_t)(b * L_ + k_abs) * DOUT_ + h * DH_;
#pragma unroll
      for (int dt = 0; dt < 3; ++dt)
        orow[dt * 16 + l15] = Oacc[i][dt][r] * msk;
    }
  }
}

// ---------------------------------------------------------------------------
// launch
// ---------------------------------------------------------------------------
extern "C" void kernel_launch(void* const* d_in, const int* in_sizes, int n_in,
                              void* d_out, int out_size, void* d_ws, size_t ws_size,
                              hipStream_t stream) {
  const float* Qs  = (const float*)d_in[0];
  const float* Kse = (const float*)d_in[1];
  const float* Vs  = (const float*)d_in[2];
  const float* WQ  = (const float*)d_in[3];
  const float* WK  = (const float*)d_in[4];
  const float* WV  = (const float*)d_in[5];
  const int*   Qlen = (const int*)d_in[6];
  const int*   Vlen = (const int*)d_in[7];
  float* out = (float*)d_out;

  char* ws = (char*)d_ws;
  int* lens = (int*)ws;
  uint16_t* qh = (uint16_t*)(ws + 256);
  uint16_t* kh = qh + (size_t)B_ * H_ * L_ * DH_;
  uint16_t* vh = kh + (size_t)B_ * H_ * L_ * DH_;
  uint16_t* Wt = vh + (size_t)B_ * H_ * L_ * DH_;

  lens_kernel<<<1, 64, 0, stream>>>(Qlen, Vlen, lens);
  wconv_kernel<<<dim3(3, 192, 3), 256, 0, stream>>>(WQ, WK, WV, Wt);
  mfma_proj<<<dim3(16384 / 128, DOUT_ / 128, 3), 256, 0, stream>>>(
      Qs, Kse, Vs, Wt, qh, kh, vh);
  attn_mfma<<<NHEADS, 256, 0, stream>>>(qh, kh, vh, lens, out);
}